// Round 1
// baseline (1163.354 us; speedup 1.0000x reference)
//
#include <hip/hip_runtime.h>
#include <math.h>

// Problem constants (fixed by the reference setup_inputs).
#define BDIM 8
#define CIN  256
#define COUT 256
#define NDIM 8192
#define DDIM 3

#define NEG_COEF 0.8f   // (1 - NEG_SLOPE)
#define LRELU_EPS 1e-6f
#define BN_EPS    1e-5f

// GEMM tiling: 64(o) x 64(n) block tile, K-chunks of 32, 256 threads,
// each thread owns a 4x4 (o,n) sub-tile for all 3 vector components.
#define OT 64
#define NT 64
#define KT 32
#define LDSP 68   // padded row stride (floats) -> 16B-aligned float4 rows, no pow2 bank stride

// ws layout (floats): [0,256) sum ; [256,512) sumsq ; [512,768) mean ; [768,1024) scale

__global__ __launch_bounds__(256) void vn_stats_kernel(
    const float* __restrict__ x, const float* __restrict__ Wf,
    float* __restrict__ ws)
{
    __shared__ float sW[KT][LDSP];        // [c][o]  (W tile transposed)
    __shared__ float sX[DDIM][KT][LDSP];  // [d][c][n]
    __shared__ float red[2][OT];

    const int t  = threadIdx.x;
    const int n0 = blockIdx.x * NT;
    const int o0 = blockIdx.y * OT;
    const int b  = blockIdx.z;

    const int tn = t & 15;   // n-sub: 0..15 -> n = n0 + tn*4 + in
    const int to = t >> 4;   // o-sub: 0..15 -> o = o0 + to*4 + io

    float acc[DDIM][4][4];
    #pragma unroll
    for (int d = 0; d < DDIM; ++d)
        #pragma unroll
        for (int i = 0; i < 4; ++i)
            #pragma unroll
            for (int j = 0; j < 4; ++j) acc[d][i][j] = 0.f;

    for (int c0 = 0; c0 < CIN; c0 += KT) {
        __syncthreads();
        #pragma unroll
        for (int i = 0; i < 8; ++i) {           // 64x32 W tile
            int e = t + i * 256;
            int c = e & 31, o = e >> 5;
            sW[c][o] = Wf[(o0 + o) * CIN + (c0 + c)];
        }
        #pragma unroll
        for (int i = 0; i < 24; ++i) {          // 3x32x64 X tile
            int e = t + i * 256;
            int n = e & 63, c = (e >> 6) & 31, d = e >> 11;
            sX[d][c][n] = x[(((size_t)b * CIN + (c0 + c)) * DDIM + d) * NDIM + n0 + n];
        }
        __syncthreads();
        #pragma unroll
        for (int k = 0; k < KT; ++k) {
            float4 w4 = *(const float4*)&sW[k][to * 4];
            float4 xa = *(const float4*)&sX[0][k][tn * 4];
            float4 xb = *(const float4*)&sX[1][k][tn * 4];
            float4 xc = *(const float4*)&sX[2][k][tn * 4];
            const float w[4]  = {w4.x, w4.y, w4.z, w4.w};
            const float x0[4] = {xa.x, xa.y, xa.z, xa.w};
            const float x1[4] = {xb.x, xb.y, xb.z, xb.w};
            const float x2[4] = {xc.x, xc.y, xc.z, xc.w};
            #pragma unroll
            for (int io = 0; io < 4; ++io) {
                #pragma unroll
                for (int in = 0; in < 4; ++in) {
                    acc[0][io][in] = fmaf(w[io], x0[in], acc[0][io][in]);
                    acc[1][io][in] = fmaf(w[io], x1[in], acc[1][io][in]);
                    acc[2][io][in] = fmaf(w[io], x2[in], acc[2][io][in]);
                }
            }
        }
    }

    // Per-thread: sum of norms / norms^2 over this thread's 4 n's, per o.
    float snorm[4], ssq[4];
    #pragma unroll
    for (int io = 0; io < 4; ++io) { snorm[io] = 0.f; ssq[io] = 0.f; }
    #pragma unroll
    for (int io = 0; io < 4; ++io)
        #pragma unroll
        for (int in = 0; in < 4; ++in) {
            float p0 = acc[0][io][in], p1 = acc[1][io][in], p2 = acc[2][io][in];
            float n2 = p0 * p0 + p1 * p1 + p2 * p2;
            snorm[io] += sqrtf(n2);
            ssq[io]   += n2;
        }
    // Reduce over tn (16 contiguous lanes) via shuffle.
    #pragma unroll
    for (int m = 1; m < 16; m <<= 1) {
        #pragma unroll
        for (int io = 0; io < 4; ++io) {
            snorm[io] += __shfl_xor(snorm[io], m, 64);
            ssq[io]   += __shfl_xor(ssq[io],   m, 64);
        }
    }
    if (tn == 0) {
        #pragma unroll
        for (int io = 0; io < 4; ++io) {
            red[0][to * 4 + io] = snorm[io];
            red[1][to * 4 + io] = ssq[io];
        }
    }
    __syncthreads();
    if (t < OT) {
        atomicAdd(&ws[o0 + t],        red[0][t]);
        atomicAdd(&ws[256 + o0 + t],  red[1][t]);
    }
}

__global__ __launch_bounds__(256) void vn_finalize_kernel(
    float* __restrict__ ws, const float* __restrict__ gamma)
{
    int o = threadIdx.x;
    const float inv_cnt = 1.0f / (float)(BDIM * NDIM);
    float mean = ws[o] * inv_cnt;
    float var  = ws[256 + o] * inv_cnt - mean * mean;
    ws[512 + o] = mean;
    ws[768 + o] = gamma[o] * rsqrtf(var + BN_EPS);
}

__global__ __launch_bounds__(256) void vn_apply_kernel(
    const float* __restrict__ x, const float* __restrict__ Wf,
    const float* __restrict__ Wd, const float* __restrict__ ws,
    const float* __restrict__ beta, float* __restrict__ out)
{
    __shared__ float sWf[KT][LDSP];       // [c][o]
    __shared__ float sWd[KT][LDSP];       // [c][o]
    __shared__ float sX[DDIM][KT][LDSP];  // [d][c][n]

    const int t  = threadIdx.x;
    const int n0 = blockIdx.x * NT;
    const int o0 = blockIdx.y * OT;
    const int b  = blockIdx.z;

    const int tn = t & 15;
    const int to = t >> 4;

    float accP[DDIM][4][4];
    float accD[DDIM][4][4];
    #pragma unroll
    for (int d = 0; d < DDIM; ++d)
        #pragma unroll
        for (int i = 0; i < 4; ++i)
            #pragma unroll
            for (int j = 0; j < 4; ++j) { accP[d][i][j] = 0.f; accD[d][i][j] = 0.f; }

    for (int c0 = 0; c0 < CIN; c0 += KT) {
        __syncthreads();
        #pragma unroll
        for (int i = 0; i < 8; ++i) {
            int e = t + i * 256;
            int c = e & 31, o = e >> 5;
            sWf[c][o] = Wf[(o0 + o) * CIN + (c0 + c)];
            sWd[c][o] = Wd[(o0 + o) * CIN + (c0 + c)];
        }
        #pragma unroll
        for (int i = 0; i < 24; ++i) {
            int e = t + i * 256;
            int n = e & 63, c = (e >> 6) & 31, d = e >> 11;
            sX[d][c][n] = x[(((size_t)b * CIN + (c0 + c)) * DDIM + d) * NDIM + n0 + n];
        }
        __syncthreads();
        #pragma unroll
        for (int k = 0; k < KT; ++k) {
            float4 wf4 = *(const float4*)&sWf[k][to * 4];
            float4 wd4 = *(const float4*)&sWd[k][to * 4];
            float4 xa  = *(const float4*)&sX[0][k][tn * 4];
            float4 xb  = *(const float4*)&sX[1][k][tn * 4];
            float4 xc  = *(const float4*)&sX[2][k][tn * 4];
            const float wf[4] = {wf4.x, wf4.y, wf4.z, wf4.w};
            const float wd[4] = {wd4.x, wd4.y, wd4.z, wd4.w};
            const float x0[4] = {xa.x, xa.y, xa.z, xa.w};
            const float x1[4] = {xb.x, xb.y, xb.z, xb.w};
            const float x2[4] = {xc.x, xc.y, xc.z, xc.w};
            #pragma unroll
            for (int io = 0; io < 4; ++io) {
                #pragma unroll
                for (int in = 0; in < 4; ++in) {
                    accP[0][io][in] = fmaf(wf[io], x0[in], accP[0][io][in]);
                    accP[1][io][in] = fmaf(wf[io], x1[in], accP[1][io][in]);
                    accP[2][io][in] = fmaf(wf[io], x2[in], accP[2][io][in]);
                    accD[0][io][in] = fmaf(wd[io], x0[in], accD[0][io][in]);
                    accD[1][io][in] = fmaf(wd[io], x1[in], accD[1][io][in]);
                    accD[2][io][in] = fmaf(wd[io], x2[in], accD[2][io][in]);
                }
            }
        }
    }

    #pragma unroll
    for (int io = 0; io < 4; ++io) {
        const int o = o0 + to * 4 + io;
        const float mean  = ws[512 + o];
        const float scale = ws[768 + o];
        const float bet   = beta[o];
        float po[DDIM][4];
        #pragma unroll
        for (int in = 0; in < 4; ++in) {
            float p0 = accP[0][io][in], p1 = accP[1][io][in], p2 = accP[2][io][in];
            float d0 = accD[0][io][in], d1 = accD[1][io][in], d2 = accD[2][io][in];
            float n2 = p0 * p0 + p1 * p1 + p2 * p2;
            float nr = sqrtf(n2);
            float nbn = (nr - mean) * scale + bet;
            float f = nbn / nr;
            p0 *= f; p1 *= f; p2 *= f;
            float dot = p0 * d0 + p1 * d1 + p2 * d2;
            if (dot < 0.f) {
                float g = NEG_COEF * dot / (d0 * d0 + d1 * d1 + d2 * d2 + LRELU_EPS);
                p0 -= g * d0; p1 -= g * d1; p2 -= g * d2;
            }
            po[0][in] = p0; po[1][in] = p1; po[2][in] = p2;
        }
        #pragma unroll
        for (int d = 0; d < DDIM; ++d) {
            float4 v = make_float4(po[d][0], po[d][1], po[d][2], po[d][3]);
            *(float4*)&out[(((size_t)b * COUT + o) * DDIM + d) * NDIM + n0 + tn * 4] = v;
        }
    }
}

extern "C" void kernel_launch(void* const* d_in, const int* in_sizes, int n_in,
                              void* d_out, int out_size, void* d_ws, size_t ws_size,
                              hipStream_t stream) {
    const float* x     = (const float*)d_in[0];
    const float* Wf    = (const float*)d_in[1];
    const float* Wd    = (const float*)d_in[2];
    const float* gamma = (const float*)d_in[3];
    const float* beta  = (const float*)d_in[4];
    float* out = (float*)d_out;
    float* ws  = (float*)d_ws;

    hipMemsetAsync(ws, 0, 512 * sizeof(float), stream);

    dim3 grid(NDIM / NT, COUT / OT, BDIM);
    vn_stats_kernel<<<grid, 256, 0, stream>>>(x, Wf, ws);
    vn_finalize_kernel<<<1, 256, 0, stream>>>(ws, gamma);
    vn_apply_kernel<<<grid, 256, 0, stream>>>(x, Wf, Wd, ws, beta, out);
}

// Round 3
// 600.352 us; speedup vs baseline: 1.9378x; 1.9378x over previous
//
#include <hip/hip_runtime.h>
#include <math.h>

#define BDIM 8
#define CIN  256
#define COUT 256
#define NDIM 8192

#define NEG_COEF  0.8f
#define LRELU_EPS 1e-6f
#define BN_EPS    1e-5f

typedef __attribute__((ext_vector_type(8))) short bf16x8;   // 8 bf16 = 4 VGPRs
typedef __attribute__((ext_vector_type(4))) float f32x4;

// ws layout: ushort offsets for W arrays (each 256*256 = 65536 ushorts = 128 KB)
#define WS_WFH 0
#define WS_WFL 65536
#define WS_WDH 131072
#define WS_WDL 196608
#define WS_STATS_BYTE 524288
#define NSLOT 8
// stats float region: sum[8][256] @0, sumsq[8][256] @2048, mean @4096, scale @4352

__device__ __forceinline__ unsigned short f2bf(float f) {
    unsigned u = __float_as_uint(f);
    return (unsigned short)((u + 0x7FFFu + ((u >> 16) & 1u)) >> 16);
}
__device__ __forceinline__ float bf2f(unsigned short h) {
    return __uint_as_float(((unsigned)h) << 16);
}

// Convert W[o][c] fp32 -> bf16 hi/lo in fragment k-order.
// pi: within each 32-k tile, k = kb + 8i  <->  position 4*kb + i.
// (Applied identically to A and B sides, so the MFMA dot product is invariant.)
__global__ __launch_bounds__(256) void setup_w_kernel(
    const float* __restrict__ Wf, const float* __restrict__ Wd,
    unsigned short* __restrict__ wsu)
{
    const int o = blockIdx.x;     // 0..255
    const int mat = blockIdx.y;   // 0 feat, 1 dir
    const int c = threadIdx.x;    // 0..255
    const float* W = mat ? Wd : Wf;
    float w = W[o * CIN + c];
    unsigned short hi = f2bf(w);
    unsigned short lo = f2bf(w - bf2f(hi));
    int pos = (c & ~31) + 4 * (c & 7) + ((c >> 3) & 3);
    unsigned short* ph = wsu + (mat ? WS_WDH : WS_WFH);
    unsigned short* pl = wsu + (mat ? WS_WDL : WS_WFL);
    ph[o * CIN + pos] = hi;
    pl[o * CIN + pos] = lo;
}

// Phase 1: p~ = Whi * Xhi (single product), per-channel sum/sumsq of vector norms.
// Block tile: 64 o x (3 d x 64 n). Wave: 32 o x (3 d x 32 n) = 2 m-tiles x 6 n-tiles.
__global__ __launch_bounds__(256) void vn_stats_mfma(
    const float* __restrict__ x, const unsigned short* __restrict__ wsu,
    float* __restrict__ stats)
{
    __shared__ unsigned short sXhi[192 * 40];   // row = 32 bf16 (pi-order) + 8 pad; 80 B/row
    __shared__ float redS[64], redQ[64];

    const int t  = threadIdx.x;
    const int n0 = blockIdx.x * 64;
    const int o0 = blockIdx.y * 64;
    const int b  = blockIdx.z;

    const int lane = t & 63;
    const int w    = t >> 6;
    const int q    = lane >> 4;
    const int ln   = lane & 15;

    const int jl = t & 31;    // staging j-lane
    const int kb = t >> 5;    // staging k-base 0..7

    if (t < 64) { redS[t] = 0.f; redQ[t] = 0.f; }

    f32x4 acc[2][6];
    #pragma unroll
    for (int i = 0; i < 2; ++i)
        #pragma unroll
        for (int j = 0; j < 6; ++j) acc[i][j] = (f32x4)0.f;

    const unsigned short* wfh = wsu + WS_WFH;
    const int oo = o0 + (w >> 1) * 32;
    const int nb = (w & 1) * 32;

    for (int c0 = 0; c0 < CIN; c0 += 32) {
        __syncthreads();
        #pragma unroll
        for (int ip = 0; ip < 6; ++ip) {
            int jloc = ip * 32 + jl;
            int d = jloc >> 6, nl = jloc & 63;
            float v[4];
            #pragma unroll
            for (int i = 0; i < 4; ++i) {
                int c = c0 + kb + 8 * i;
                v[i] = x[((size_t)((b * CIN + c) * 3 + d)) * NDIM + n0 + nl];
            }
            unsigned p0 = (unsigned)f2bf(v[0]) | ((unsigned)f2bf(v[1]) << 16);
            unsigned p1 = (unsigned)f2bf(v[2]) | ((unsigned)f2bf(v[3]) << 16);
            *(uint2*)&sXhi[jloc * 40 + kb * 4] = make_uint2(p0, p1);
        }
        __syncthreads();
        bf16x8 af[2];
        #pragma unroll
        for (int mt = 0; mt < 2; ++mt)
            af[mt] = *(const bf16x8*)&wfh[(oo + mt * 16 + ln) * CIN + c0 + q * 8];
        #pragma unroll
        for (int nt = 0; nt < 6; ++nt) {
            int d = nt >> 1, h = nt & 1;
            int jloc = d * 64 + nb + h * 16 + ln;
            bf16x8 bh = *(const bf16x8*)&sXhi[jloc * 40 + q * 8];
            #pragma unroll
            for (int mt = 0; mt < 2; ++mt)
                acc[mt][nt] = __builtin_amdgcn_mfma_f32_16x16x32_bf16(af[mt], bh, acc[mt][nt], 0, 0, 0);
        }
    }

    // Per-lane norms: D layout row = q*4 + r (o), col = ln (n).
    #pragma unroll
    for (int mt = 0; mt < 2; ++mt) {
        #pragma unroll
        for (int r = 0; r < 4; ++r) {
            float s = 0.f, s2 = 0.f;
            #pragma unroll
            for (int h = 0; h < 2; ++h) {
                float p0 = acc[mt][0 + h][r];
                float p1 = acc[mt][2 + h][r];
                float p2 = acc[mt][4 + h][r];
                float n2 = p0 * p0 + p1 * p1 + p2 * p2;
                s += sqrtf(n2); s2 += n2;
            }
            #pragma unroll
            for (int m = 1; m < 16; m <<= 1) {
                s  += __shfl_xor(s,  m, 64);
                s2 += __shfl_xor(s2, m, 64);
            }
            if (ln == 0) {
                // FIX (R2 NaN bug): include the wave's 32-channel m-offset.
                // Without (w>>1)*32, waves 2-3 doubled channels 0..31 (=> var<0
                // => rsqrtf NaN) and left channels 32..63 empty.
                int ol = (w >> 1) * 32 + mt * 16 + q * 4 + r;
                atomicAdd(&redS[ol], s);
                atomicAdd(&redQ[ol], s2);
            }
        }
    }
    __syncthreads();
    if (t < 64) {
        int slot = blockIdx.x & (NSLOT - 1);
        atomicAdd(&stats[slot * 256 + o0 + t], redS[t]);
        atomicAdd(&stats[NSLOT * 256 + slot * 256 + o0 + t], redQ[t]);
    }
}

__global__ __launch_bounds__(256) void vn_finalize2(
    float* __restrict__ stats, const float* __restrict__ gamma)
{
    int o = threadIdx.x;
    float s = 0.f, s2 = 0.f;
    #pragma unroll
    for (int i = 0; i < NSLOT; ++i) {
        s  += stats[i * 256 + o];
        s2 += stats[(NSLOT + i) * 256 + o];
    }
    const float inv = 1.0f / (float)(BDIM * NDIM);
    float mean = s * inv;
    float var  = fmaxf(s2 * inv - mean * mean, 0.f);
    stats[2 * NSLOT * 256 + o] = mean;
    stats[2 * NSLOT * 256 + 256 + o] = gamma[o] * rsqrtf(var + BN_EPS);
}

// Phase 2: p (4-product split), d (3-product split), fused BN + VN-LeakyReLU.
__global__ __launch_bounds__(256) void vn_main_mfma(
    const float* __restrict__ x, const unsigned short* __restrict__ wsu,
    const float* __restrict__ stats, const float* __restrict__ beta,
    float* __restrict__ out)
{
    __shared__ unsigned short sXhi[192 * 40];
    __shared__ unsigned short sXlo[192 * 40];

    const int t  = threadIdx.x;
    const int n0 = blockIdx.x * 64;
    const int o0 = blockIdx.y * 64;
    const int b  = blockIdx.z;

    const int lane = t & 63;
    const int w    = t >> 6;
    const int q    = lane >> 4;
    const int ln   = lane & 15;

    const int jl = t & 31;
    const int kb = t >> 5;

    f32x4 accP[2][6], accD[2][6];
    #pragma unroll
    for (int i = 0; i < 2; ++i)
        #pragma unroll
        for (int j = 0; j < 6; ++j) { accP[i][j] = (f32x4)0.f; accD[i][j] = (f32x4)0.f; }

    const unsigned short* wfh = wsu + WS_WFH;
    const unsigned short* wfl = wsu + WS_WFL;
    const unsigned short* wdh = wsu + WS_WDH;
    const unsigned short* wdl = wsu + WS_WDL;
    const int oo = o0 + (w >> 1) * 32;
    const int nb = (w & 1) * 32;

    for (int c0 = 0; c0 < CIN; c0 += 32) {
        __syncthreads();
        #pragma unroll
        for (int ip = 0; ip < 6; ++ip) {
            int jloc = ip * 32 + jl;
            int d = jloc >> 6, nl = jloc & 63;
            float v[4];
            #pragma unroll
            for (int i = 0; i < 4; ++i) {
                int c = c0 + kb + 8 * i;
                v[i] = x[((size_t)((b * CIN + c) * 3 + d)) * NDIM + n0 + nl];
            }
            unsigned short h0 = f2bf(v[0]), h1 = f2bf(v[1]), h2 = f2bf(v[2]), h3 = f2bf(v[3]);
            unsigned ph0 = (unsigned)h0 | ((unsigned)h1 << 16);
            unsigned ph1 = (unsigned)h2 | ((unsigned)h3 << 16);
            unsigned pl0 = (unsigned)f2bf(v[0] - bf2f(h0)) | ((unsigned)f2bf(v[1] - bf2f(h1)) << 16);
            unsigned pl1 = (unsigned)f2bf(v[2] - bf2f(h2)) | ((unsigned)f2bf(v[3] - bf2f(h3)) << 16);
            *(uint2*)&sXhi[jloc * 40 + kb * 4] = make_uint2(ph0, ph1);
            *(uint2*)&sXlo[jloc * 40 + kb * 4] = make_uint2(pl0, pl1);
        }
        __syncthreads();
        bf16x8 afh[2], afl[2], adh[2], adl[2];
        #pragma unroll
        for (int mt = 0; mt < 2; ++mt) {
            int row = (oo + mt * 16 + ln) * CIN + c0 + q * 8;
            afh[mt] = *(const bf16x8*)&wfh[row];
            afl[mt] = *(const bf16x8*)&wfl[row];
            adh[mt] = *(const bf16x8*)&wdh[row];
            adl[mt] = *(const bf16x8*)&wdl[row];
        }
        #pragma unroll
        for (int nt = 0; nt < 6; ++nt) {
            int d = nt >> 1, h = nt & 1;
            int jloc = d * 64 + nb + h * 16 + ln;
            bf16x8 bh = *(const bf16x8*)&sXhi[jloc * 40 + q * 8];
            bf16x8 bl = *(const bf16x8*)&sXlo[jloc * 40 + q * 8];
            #pragma unroll
            for (int mt = 0; mt < 2; ++mt) {
                f32x4 aP = accP[mt][nt];
                aP = __builtin_amdgcn_mfma_f32_16x16x32_bf16(afh[mt], bh, aP, 0, 0, 0);
                aP = __builtin_amdgcn_mfma_f32_16x16x32_bf16(afh[mt], bl, aP, 0, 0, 0);
                aP = __builtin_amdgcn_mfma_f32_16x16x32_bf16(afl[mt], bh, aP, 0, 0, 0);
                aP = __builtin_amdgcn_mfma_f32_16x16x32_bf16(afl[mt], bl, aP, 0, 0, 0);
                accP[mt][nt] = aP;
                f32x4 aD = accD[mt][nt];
                aD = __builtin_amdgcn_mfma_f32_16x16x32_bf16(adh[mt], bh, aD, 0, 0, 0);
                aD = __builtin_amdgcn_mfma_f32_16x16x32_bf16(adh[mt], bl, aD, 0, 0, 0);
                aD = __builtin_amdgcn_mfma_f32_16x16x32_bf16(adl[mt], bh, aD, 0, 0, 0);
                accD[mt][nt] = aD;
            }
        }
    }

    const float* meanp  = stats + 2 * NSLOT * 256;
    const float* scalep = meanp + 256;
    #pragma unroll
    for (int mt = 0; mt < 2; ++mt) {
        #pragma unroll
        for (int r = 0; r < 4; ++r) {
            const int o = oo + mt * 16 + q * 4 + r;
            const float mean  = meanp[o];
            const float scale = scalep[o];
            const float bet   = beta[o];
            #pragma unroll
            for (int h = 0; h < 2; ++h) {
                float p0 = accP[mt][0 + h][r], p1 = accP[mt][2 + h][r], p2 = accP[mt][4 + h][r];
                float d0 = accD[mt][0 + h][r], d1 = accD[mt][2 + h][r], d2 = accD[mt][4 + h][r];
                float n2 = p0 * p0 + p1 * p1 + p2 * p2;
                float nr = sqrtf(n2);
                float f  = ((nr - mean) * scale + bet) / nr;
                p0 *= f; p1 *= f; p2 *= f;
                float dot = p0 * d0 + p1 * d1 + p2 * d2;
                if (dot < 0.f) {
                    float g = NEG_COEF * dot / (d0 * d0 + d1 * d1 + d2 * d2 + LRELU_EPS);
                    p0 -= g * d0; p1 -= g * d1; p2 -= g * d2;
                }
                const int n = n0 + nb + h * 16 + ln;
                out[((size_t)(b * COUT + o) * 3 + 0) * NDIM + n] = p0;
                out[((size_t)(b * COUT + o) * 3 + 1) * NDIM + n] = p1;
                out[((size_t)(b * COUT + o) * 3 + 2) * NDIM + n] = p2;
            }
        }
    }
}

extern "C" void kernel_launch(void* const* d_in, const int* in_sizes, int n_in,
                              void* d_out, int out_size, void* d_ws, size_t ws_size,
                              hipStream_t stream) {
    const float* x     = (const float*)d_in[0];
    const float* Wf    = (const float*)d_in[1];
    const float* Wd    = (const float*)d_in[2];
    const float* gamma = (const float*)d_in[3];
    const float* beta  = (const float*)d_in[4];
    float* out = (float*)d_out;
    unsigned short* wsu = (unsigned short*)d_ws;
    float* stats = (float*)((char*)d_ws + WS_STATS_BYTE);

    hipMemsetAsync((char*)d_ws + WS_STATS_BYTE, 0, 2 * NSLOT * 256 * sizeof(float), stream);

    setup_w_kernel<<<dim3(256, 2), 256, 0, stream>>>(Wf, Wd, wsu);
    dim3 grid(NDIM / 64, COUT / 64, BDIM);
    vn_stats_mfma<<<grid, 256, 0, stream>>>(x, wsu, stats);
    vn_finalize2<<<1, 256, 0, stream>>>(stats, gamma);
    vn_main_mfma<<<grid, 256, 0, stream>>>(x, wsu, stats, beta, out);
}